// Round 13
// baseline (305.849 us; speedup 1.0000x reference)
//
#include <hip/hip_runtime.h>

// GCN forward via two-level CSR build + gather aggregation (no atomics in the
// float path — R4/R9: atomic aggregation loses 5-10x to register gather).
//   binA2: per-block LDS radix partition -> 256 dst-range buckets.
//   buildB: per-bucket LDS histogram+scan -> counts/offs/dinv + CSR
//     (bucket-base prefix computed inline; bucket_scan kernel removed).
//   gemm1: (x@W1)*dinv -> xwdA (feats 0-15) + xwdB (feats 16-31), bf16 32B
//     rows. Each array = 3.2 MB < 4 MiB per-XCD L2 --> the layer-1 gather
//     runs as TWO L2-resident passes (R12: single 64B-row pass was capacity-
//     limited at 3.2 TB/s, FETCH 152 MB).
//   aggH (x2): lane-slice, 2 lanes/node, serial edges, zero reduction
//     shuffles; writes agg1 half-rows fp32.
//   gemm2: h2wd = (relu(agg1+b1)@W2)*dinv, bf16 32B rows (L2-resident).
//   aggS16f: 2 lanes/node + fused head (8 FMA + 1 shfl_xor) -> out.
// R7 lesson: no wave-serial (multi-step broadcast) epilogues in gather kernels.

#define TPB 256
#define NBUCK 256
#define BCAP 16384   // bucket capacity; mean ~12512 -> large margin
#define CHUNK 8192   // edges per binA2 block

__device__ __forceinline__ unsigned f2bf(float f) {  // RNE fp32->bf16
    unsigned u = __float_as_uint(f);
    return (u + 0x7FFFu + ((u >> 16) & 1u)) >> 16;
}
__device__ __forceinline__ float bflo(unsigned u) { return __uint_as_float(u << 16); }
__device__ __forceinline__ float bfhi(unsigned u) { return __uint_as_float(u & 0xFFFF0000u); }

// Phase A: block-local radix partition, then bulk append to global staging.
__global__ __launch_bounds__(256) void binA2_kernel(
        const int* __restrict__ src, const int* __restrict__ dst,
        int* __restrict__ bcur, unsigned* __restrict__ staging, int E, int NPB) {
    __shared__ unsigned packed[CHUNK];
    __shared__ unsigned char buckb[CHUNK];
    __shared__ int hist[NBUCK];
    __shared__ int scan_[NBUCK];
    __shared__ int lstart[NBUCK];
    __shared__ int lcur[NBUCK];
    __shared__ int gbase[NBUCK];
    int tid = threadIdx.x;
    int start = blockIdx.x * CHUNK;
    int sz = min(CHUNK, E - start);

    hist[tid] = 0;
    __syncthreads();
    for (int i = tid; i < sz; i += 256) {
        unsigned d = (unsigned)dst[start + i];
        atomicAdd(&hist[d / (unsigned)NPB], 1);
    }
    __syncthreads();
    int v = hist[tid];
    scan_[tid] = v;
    __syncthreads();
    for (int dd = 1; dd < NBUCK; dd <<= 1) {
        int t = 0;
        if (tid >= dd) t = scan_[tid - dd];
        __syncthreads();
        scan_[tid] += t;
        __syncthreads();
    }
    lstart[tid] = scan_[tid] - v;
    lcur[tid] = 0;
    gbase[tid] = atomicAdd(&bcur[tid], v);  // reserve once per (block,bucket)
    __syncthreads();
    for (int i = tid; i < sz; i += 256) {
        unsigned d = (unsigned)dst[start + i];
        unsigned s = (unsigned)src[start + i];
        unsigned b = d / (unsigned)NPB;
        unsigned loc = d - b * (unsigned)NPB;
        int pos = atomicAdd(&lcur[b], 1);
        int si = lstart[b] + pos;
        packed[si] = (loc << 20) | s;
        buckb[si] = (unsigned char)b;
    }
    __syncthreads();
    for (int i = tid; i < sz; i += 256) {
        unsigned b = buckb[i];
        int dsti = gbase[b] + (i - lstart[b]);
        if (dsti < BCAP)
            staging[(size_t)b * BCAP + dsti] = packed[i];
    }
}

// Phase B: one block (512 thr) per bucket. Inline bucket-base prefix, then
// histogram + scan + CSR placement.
__global__ void buildB_kernel(const int* __restrict__ bcur,
                              const unsigned* __restrict__ staging,
                              int* __restrict__ offs, int* __restrict__ counts,
                              float* __restrict__ dinv, int* __restrict__ csr_src,
                              int N, int NPB) {
    __shared__ int sb[NBUCK];
    __shared__ int hist[512];
    __shared__ int scan_[512];
    __shared__ int cur[512];
    int b = blockIdx.x;
    int tid = threadIdx.x;
    // inclusive prefix of clamped bucket sizes over 256 entries
    if (tid < NBUCK) sb[tid] = min(bcur[tid], BCAP);
    __syncthreads();
    for (int d = 1; d < NBUCK; d <<= 1) {
        int t = 0;
        if (tid < NBUCK && tid >= d) t = sb[tid - d];
        __syncthreads();
        if (tid < NBUCK) sb[tid] += t;
        __syncthreads();
    }
    int sz = min(bcur[b], BCAP);
    int base = (b == 0) ? 0 : sb[b - 1];
    int n0 = b * NPB;
    int nn = min(NPB, N - n0);
    const unsigned* se = staging + (size_t)b * BCAP;

    hist[tid] = 0;
    __syncthreads();
    for (int i = tid; i < sz; i += 512)
        atomicAdd(&hist[se[i] >> 20], 1);
    __syncthreads();
    int h = hist[tid];
    scan_[tid] = h;
    __syncthreads();
    for (int d = 1; d < 512; d <<= 1) {
        int t = 0;
        if (tid >= d) t = scan_[tid - d];
        __syncthreads();
        scan_[tid] += t;
        __syncthreads();
    }
    int excl = scan_[tid] - h;
    cur[tid] = excl;
    if (tid < nn) {
        int node = n0 + tid;
        offs[node] = base + excl;
        counts[node] = h;
        dinv[node] = rsqrtf((float)(h + 1));  // +1 self-loop
    }
    __syncthreads();
    for (int i = tid; i < sz; i += 512) {
        unsigned p = se[i];
        int pos = atomicAdd(&cur[p >> 20], 1);
        csr_src[base + pos] = (int)(p & 0xFFFFFu);
    }
}

// (x @ W1) * dinv -> xwdA (cols 0-15) / xwdB (cols 16-31), bf16 32B rows.
// 4 threads/node x 8 cols; grid (N+63)/64.
__global__ __launch_bounds__(256) void gemm1_kernel(
        const float* __restrict__ x, const float* __restrict__ W1,
        const float* __restrict__ dinv, unsigned* __restrict__ xwdA,
        unsigned* __restrict__ xwdB, int N) {
    __shared__ float ws_[128 * 32];
    for (int i = threadIdx.x; i < 128 * 32; i += blockDim.x) ws_[i] = W1[i];
    __syncthreads();
    int t = threadIdx.x;
    int node = blockIdx.x * 64 + (t >> 2);
    if (node >= N) return;
    int slice = t & 3;
    int jq = slice * 8;  // 8 output cols
    float acc[8];
#pragma unroll
    for (int j = 0; j < 8; ++j) acc[j] = 0.0f;
    const float4* xr = (const float4*)(x + (size_t)node * 128);
#pragma unroll 4
    for (int k4 = 0; k4 < 32; ++k4) {
        float4 xv = xr[k4];
        const float* wb = ws_ + (k4 * 4) * 32 + jq;
        float4 a0 = *(const float4*)(wb);
        float4 a1 = *(const float4*)(wb + 4);
        float4 b0 = *(const float4*)(wb + 32);
        float4 b1v = *(const float4*)(wb + 36);
        float4 c0 = *(const float4*)(wb + 64);
        float4 c1 = *(const float4*)(wb + 68);
        float4 d0 = *(const float4*)(wb + 96);
        float4 d1 = *(const float4*)(wb + 100);
        acc[0] += xv.x * a0.x + xv.y * b0.x + xv.z * c0.x + xv.w * d0.x;
        acc[1] += xv.x * a0.y + xv.y * b0.y + xv.z * c0.y + xv.w * d0.y;
        acc[2] += xv.x * a0.z + xv.y * b0.z + xv.z * c0.z + xv.w * d0.z;
        acc[3] += xv.x * a0.w + xv.y * b0.w + xv.z * c0.w + xv.w * d0.w;
        acc[4] += xv.x * a1.x + xv.y * b1v.x + xv.z * c1.x + xv.w * d1.x;
        acc[5] += xv.x * a1.y + xv.y * b1v.y + xv.z * c1.y + xv.w * d1.y;
        acc[6] += xv.x * a1.z + xv.y * b1v.z + xv.z * c1.z + xv.w * d1.z;
        acc[7] += xv.x * a1.w + xv.y * b1v.w + xv.z * c1.w + xv.w * d1.w;
    }
    float d = dinv[node];
    unsigned pk0 = f2bf(acc[0] * d) | (f2bf(acc[1] * d) << 16);
    unsigned pk1 = f2bf(acc[2] * d) | (f2bf(acc[3] * d) << 16);
    unsigned pk2 = f2bf(acc[4] * d) | (f2bf(acc[5] * d) << 16);
    unsigned pk3 = f2bf(acc[6] * d) | (f2bf(acc[7] * d) << 16);
    unsigned* dstArr = (slice < 2) ? xwdA : xwdB;
    ((uint4*)(dstArr + (size_t)node * 8))[slice & 1] = make_uint4(pk0, pk1, pk2, pk3);
}

// Layer-1 half-gather: 2 lanes/node own a 32B bf16 row (xh = xwdA or xwdB,
// 3.2MB, L2-resident); serial edges x2 unroll; fp32 accum; no shuffles.
// Writes agg half-row: aggHalf + node*32 + q*8 (aggHalf = agg1 + half*16).
__global__ __launch_bounds__(256) void aggH_kernel(
        const int* __restrict__ offs, const int* __restrict__ counts,
        const int* __restrict__ csr_src, const float* __restrict__ dinv,
        const unsigned* __restrict__ xh, float* __restrict__ aggHalf, int N) {
    int t = threadIdx.x;
    int q = t & 1;                        // 16B slice (8 bf16)
    int node = blockIdx.x * 128 + (t >> 1);
    if (node >= N) return;
    int off = offs[node];
    int deg = counts[node];
    float acc[8];
    {
        uint4 v = ((const uint4*)(xh + (size_t)node * 8))[q];  // self term
        acc[0] = bflo(v.x); acc[1] = bfhi(v.x);
        acc[2] = bflo(v.y); acc[3] = bfhi(v.y);
        acc[4] = bflo(v.z); acc[5] = bfhi(v.z);
        acc[6] = bflo(v.w); acc[7] = bfhi(v.w);
    }
    int i = 0;
    for (; i + 1 < deg; i += 2) {
        int s0 = csr_src[off + i];
        int s1 = csr_src[off + i + 1];
        uint4 v0 = ((const uint4*)(xh + (size_t)s0 * 8))[q];
        uint4 v1 = ((const uint4*)(xh + (size_t)s1 * 8))[q];
        acc[0] += bflo(v0.x) + bflo(v1.x); acc[1] += bfhi(v0.x) + bfhi(v1.x);
        acc[2] += bflo(v0.y) + bflo(v1.y); acc[3] += bfhi(v0.y) + bfhi(v1.y);
        acc[4] += bflo(v0.z) + bflo(v1.z); acc[5] += bfhi(v0.z) + bfhi(v1.z);
        acc[6] += bflo(v0.w) + bflo(v1.w); acc[7] += bfhi(v0.w) + bfhi(v1.w);
    }
    if (i < deg) {
        int s = csr_src[off + i];
        uint4 v = ((const uint4*)(xh + (size_t)s * 8))[q];
        acc[0] += bflo(v.x); acc[1] += bfhi(v.x);
        acc[2] += bflo(v.y); acc[3] += bfhi(v.y);
        acc[4] += bflo(v.z); acc[5] += bfhi(v.z);
        acc[6] += bflo(v.w); acc[7] += bfhi(v.w);
    }
    float dv = dinv[node];
    float* op = aggHalf + (size_t)node * 32 + q * 8;
    ((float4*)op)[0] = make_float4(acc[0] * dv, acc[1] * dv, acc[2] * dv, acc[3] * dv);
    ((float4*)op)[1] = make_float4(acc[4] * dv, acc[5] * dv, acc[6] * dv, acc[7] * dv);
}

// h2wd(bf16) = (relu(agg1 + b1) @ W2) * dinv[node]
__global__ void gemm2_kernel(const float* __restrict__ agg1, const float* __restrict__ W2,
                             const float* __restrict__ b1, const float* __restrict__ dinv,
                             unsigned* __restrict__ h2wd, int N) {
    __shared__ float ws_[32 * 16];
    __shared__ float bs_[32];
    for (int i = threadIdx.x; i < 32 * 16; i += blockDim.x) ws_[i] = W2[i];
    if (threadIdx.x < 32) bs_[threadIdx.x] = b1[threadIdx.x];
    __syncthreads();
    int node = blockIdx.x * blockDim.x + threadIdx.x;
    if (node >= N) return;
    float h[32];
    const float4* ar = (const float4*)(agg1 + (size_t)node * 32);
#pragma unroll
    for (int k4 = 0; k4 < 8; ++k4) {
        float4 v = ar[k4];
        h[k4 * 4 + 0] = fmaxf(v.x + bs_[k4 * 4 + 0], 0.0f);
        h[k4 * 4 + 1] = fmaxf(v.y + bs_[k4 * 4 + 1], 0.0f);
        h[k4 * 4 + 2] = fmaxf(v.z + bs_[k4 * 4 + 2], 0.0f);
        h[k4 * 4 + 3] = fmaxf(v.w + bs_[k4 * 4 + 3], 0.0f);
    }
    float acc[16];
#pragma unroll
    for (int j = 0; j < 16; ++j) acc[j] = 0.0f;
#pragma unroll
    for (int k = 0; k < 32; ++k) {
        float hv = h[k];
#pragma unroll
        for (int j4 = 0; j4 < 4; ++j4) {
            float4 w = *(const float4*)(ws_ + k * 16 + j4 * 4);
            acc[j4 * 4 + 0] += hv * w.x;
            acc[j4 * 4 + 1] += hv * w.y;
            acc[j4 * 4 + 2] += hv * w.z;
            acc[j4 * 4 + 3] += hv * w.w;
        }
    }
    float d = dinv[node];
    unsigned pk[8];
#pragma unroll
    for (int j = 0; j < 8; ++j)
        pk[j] = f2bf(acc[2 * j] * d) | (f2bf(acc[2 * j + 1] * d) << 16);
    uint4* hp = (uint4*)(h2wd + (size_t)node * 8);
    hp[0] = make_uint4(pk[0], pk[1], pk[2], pk[3]);
    hp[1] = make_uint4(pk[4], pk[5], pk[6], pk[7]);
}

// Layer-2 aggregate + fused head, lane-slice: 2 lanes own node's 32B row;
// serial edges (x2 unroll); epilogue = 8 FMA dot + ONE shfl_xor -> out.
__global__ __launch_bounds__(256) void aggS16f_kernel(
        const int* __restrict__ offs, const int* __restrict__ counts,
        const int* __restrict__ csr_src, const float* __restrict__ dinv,
        const unsigned* __restrict__ h2wd,
        const float* __restrict__ b2, const float* __restrict__ Wf,
        const float* __restrict__ bf, float* __restrict__ out, int N) {
    __shared__ float bs_[16];
    __shared__ float wf_[16];
    __shared__ float bfv;
    int t = threadIdx.x;
    if (t < 16) { bs_[t] = b2[t]; wf_[t] = Wf[t]; }
    if (t == 0) bfv = bf[0];
    __syncthreads();
    int q = t & 1;                        // 16B slice (8 feats)
    int node = blockIdx.x * 128 + (t >> 1);
    if (node >= N) return;
    int off = offs[node];
    int deg = counts[node];
    float acc[8];
    {
        uint4 v = ((const uint4*)(h2wd + (size_t)node * 8))[q];  // self term
        acc[0] = bflo(v.x); acc[1] = bfhi(v.x);
        acc[2] = bflo(v.y); acc[3] = bfhi(v.y);
        acc[4] = bflo(v.z); acc[5] = bfhi(v.z);
        acc[6] = bflo(v.w); acc[7] = bfhi(v.w);
    }
    int i = 0;
    for (; i + 1 < deg; i += 2) {
        int s0 = csr_src[off + i];
        int s1 = csr_src[off + i + 1];
        uint4 v0 = ((const uint4*)(h2wd + (size_t)s0 * 8))[q];
        uint4 v1 = ((const uint4*)(h2wd + (size_t)s1 * 8))[q];
        acc[0] += bflo(v0.x) + bflo(v1.x); acc[1] += bfhi(v0.x) + bfhi(v1.x);
        acc[2] += bflo(v0.y) + bflo(v1.y); acc[3] += bfhi(v0.y) + bfhi(v1.y);
        acc[4] += bflo(v0.z) + bflo(v1.z); acc[5] += bfhi(v0.z) + bfhi(v1.z);
        acc[6] += bflo(v0.w) + bflo(v1.w); acc[7] += bfhi(v0.w) + bfhi(v1.w);
    }
    if (i < deg) {
        int s = csr_src[off + i];
        uint4 v = ((const uint4*)(h2wd + (size_t)s * 8))[q];
        acc[0] += bflo(v.x); acc[1] += bfhi(v.x);
        acc[2] += bflo(v.y); acc[3] += bfhi(v.y);
        acc[4] += bflo(v.z); acc[5] += bfhi(v.z);
        acc[6] += bflo(v.w); acc[7] += bfhi(v.w);
    }
    // fused head: out[node] = relu(acc*dv + b2) . Wf + bf  (pair-split dot)
    float dv = dinv[node];
    const float* bq = bs_ + q * 8;
    const float* wq = wf_ + q * 8;
    float part = 0.f;
#pragma unroll
    for (int k = 0; k < 8; ++k)
        part += fmaxf(acc[k] * dv + bq[k], 0.f) * wq[k];
    part += __shfl_xor(part, 1, 64);  // combine the pair's halves
    if (q == 0) out[node] = part + bfv;
}

extern "C" void kernel_launch(void* const* d_in, const int* in_sizes, int n_in,
                              void* d_out, int out_size, void* d_ws, size_t ws_size,
                              hipStream_t stream) {
    const float* x  = (const float*)d_in[0];
    const int*   ei = (const int*)d_in[1];
    const float* W1 = (const float*)d_in[2];
    const float* b1 = (const float*)d_in[3];
    const float* W2 = (const float*)d_in[4];
    const float* b2 = (const float*)d_in[5];
    const float* Wf = (const float*)d_in[6];
    const float* bf = (const float*)d_in[7];

    int N = in_sizes[0] / 128;
    int E = in_sizes[1] / 2;
    const int* src = ei;       // edge_index[0]
    const int* dst = ei + E;   // edge_index[1]
    int NPB = (N + NBUCK - 1) / NBUCK;  // 391 for N=100k

    // Workspace layout
    size_t Np = ((size_t)N + 3) & ~(size_t)3;
    size_t Ep = ((size_t)E + 3) & ~(size_t)3;
    int* wsI      = (int*)d_ws;
    int* counts   = wsI;                 // N
    int* offs     = counts + Np;         // N
    int* bcur     = offs + Np;           // 256
    int* csr_src  = bcur + NBUCK;        // E
    float* dinv   = (float*)(csr_src + Ep);      // N
    unsigned* xwdA= (unsigned*)(dinv + Np);      // 8*N u32 (bf16 feats 0-15)
    unsigned* xwdB= xwdA + 8 * Np;               // 8*N u32 (bf16 feats 16-31)
    float* agg1   = (float*)(xwdB + 8 * Np);     // 32*N f32
    unsigned* h2wd= (unsigned*)(agg1 + 32 * Np); // 8*N u32 (bf16 rows, 32B)
    float* out    = (float*)d_out;
    // Staging (16.8 MB) aliases agg1+h2wd (15.2 MB) + tail: written by binA2,
    // read last by buildB; agg1 first written by aggH (later). No overlap.
    unsigned* staging = (unsigned*)agg1;

    int nbG1 = (N + 63) / 64;    // 4 threads/node
    int nbC  = (E + CHUNK - 1) / CHUNK;
    int nbN  = (N + TPB - 1) / TPB;
    int nbA  = (N + 127) / 128;  // 128 nodes/block (2 lanes/node)

    hipMemsetAsync(bcur, 0, NBUCK * sizeof(int), stream);
    binA2_kernel<<<nbC, 256, 0, stream>>>(src, dst, bcur, staging, E, NPB);
    buildB_kernel<<<NBUCK, 512, 0, stream>>>(bcur, staging, offs, counts,
                                             dinv, csr_src, N, NPB);
    gemm1_kernel<<<nbG1, 256, 0, stream>>>(x, W1, dinv, xwdA, xwdB, N);
    aggH_kernel<<<nbA, 256, 0, stream>>>(offs, counts, csr_src, dinv, xwdA, agg1, N);
    aggH_kernel<<<nbA, 256, 0, stream>>>(offs, counts, csr_src, dinv, xwdB, agg1 + 16, N);
    gemm2_kernel<<<nbN, TPB, 0, stream>>>(agg1, W2, b1, dinv, h2wd, N);
    aggS16f_kernel<<<nbA, 256, 0, stream>>>(offs, counts, csr_src, dinv, h2wd,
                                            b2, Wf, bf, out, N);
}

// Round 14
// 274.269 us; speedup vs baseline: 1.1151x; 1.1151x over previous
//
#include <hip/hip_runtime.h>

// GCN forward via two-level CSR build + gather aggregation (no atomics in the
// float path — R4/R9: atomic aggregation loses 5-10x to register gather).
//   binA2: per-block LDS radix partition -> 256 dst-range buckets.
//     512 threads (R13: 256thr + 46KB LDS = 12 waves/CU, 12.7% occupancy, the
//     #2 kernel at 44us; 512thr doubles resident waves at same LDS).
//   buildB: per-bucket LDS histogram+scan -> counts/offs/dinv + CSR
//     (bucket-base prefix computed inline).
//   gemm1: xwd = (x@W1)*dinv, bf16 64B rows, 4 thr/node x 8 cols.
//   aggS32: lane-slice, 4 lanes/node, serial edges, fp32 accum, no shuffles.
//     R13 lesson: gather is request-rate bound (~53us floor) — two L2-resident
//     half-passes cost MORE (35us x2); single pass is optimal.
//   gemm2: h2wd = (relu(agg1+b1)@W2)*dinv, bf16 32B rows.
//   aggS16f: 2 lanes/node + fused head (8 FMA + 1 shfl_xor) -> out.
// R7 lesson: no wave-serial (multi-step broadcast) epilogues in gather kernels.

#define TPB 256
#define NBUCK 256
#define BCAP 16384   // bucket capacity; mean ~12512 -> large margin
#define CHUNK 8192   // edges per binA2 block

__device__ __forceinline__ unsigned f2bf(float f) {  // RNE fp32->bf16
    unsigned u = __float_as_uint(f);
    return (u + 0x7FFFu + ((u >> 16) & 1u)) >> 16;
}
__device__ __forceinline__ float bflo(unsigned u) { return __uint_as_float(u << 16); }
__device__ __forceinline__ float bfhi(unsigned u) { return __uint_as_float(u & 0xFFFF0000u); }

// Phase A: block-local radix partition, then bulk append to global staging.
// 512 threads; scan phases use the low 256 with guarded ops + full barriers.
__global__ __launch_bounds__(512) void binA2_kernel(
        const int* __restrict__ src, const int* __restrict__ dst,
        int* __restrict__ bcur, unsigned* __restrict__ staging, int E, int NPB) {
    __shared__ unsigned packed[CHUNK];        // 32 KB
    __shared__ unsigned char buckb[CHUNK];    // 8 KB
    __shared__ int hist[NBUCK];
    __shared__ int scan_[NBUCK];
    __shared__ int lstart[NBUCK];
    __shared__ int lcur[NBUCK];
    __shared__ int gbase[NBUCK];
    int tid = threadIdx.x;
    int start = blockIdx.x * CHUNK;
    int sz = min(CHUNK, E - start);

    if (tid < NBUCK) hist[tid] = 0;
    __syncthreads();
    for (int i = tid; i < sz; i += 512) {
        unsigned d = (unsigned)dst[start + i];
        atomicAdd(&hist[d / (unsigned)NPB], 1);
    }
    __syncthreads();
    int v = (tid < NBUCK) ? hist[tid] : 0;
    if (tid < NBUCK) scan_[tid] = v;
    __syncthreads();
    for (int dd = 1; dd < NBUCK; dd <<= 1) {
        int t = 0;
        if (tid < NBUCK && tid >= dd) t = scan_[tid - dd];
        __syncthreads();
        if (tid < NBUCK) scan_[tid] += t;
        __syncthreads();
    }
    if (tid < NBUCK) {
        lstart[tid] = scan_[tid] - v;
        lcur[tid] = 0;
        gbase[tid] = atomicAdd(&bcur[tid], v);  // one reservation per (block,bucket)
    }
    __syncthreads();
    for (int i = tid; i < sz; i += 512) {
        unsigned d = (unsigned)dst[start + i];
        unsigned s = (unsigned)src[start + i];
        unsigned b = d / (unsigned)NPB;
        unsigned loc = d - b * (unsigned)NPB;
        int pos = atomicAdd(&lcur[b], 1);
        int si = lstart[b] + pos;
        packed[si] = (loc << 20) | s;
        buckb[si] = (unsigned char)b;
    }
    __syncthreads();
    for (int i = tid; i < sz; i += 512) {
        unsigned b = buckb[i];
        int dsti = gbase[b] + (i - lstart[b]);
        if (dsti < BCAP)
            staging[(size_t)b * BCAP + dsti] = packed[i];
    }
}

// Phase B: one block (512 thr) per bucket. Inline bucket-base prefix, then
// histogram + scan + CSR placement.
__global__ void buildB_kernel(const int* __restrict__ bcur,
                              const unsigned* __restrict__ staging,
                              int* __restrict__ offs, int* __restrict__ counts,
                              float* __restrict__ dinv, int* __restrict__ csr_src,
                              int N, int NPB) {
    __shared__ int sb[NBUCK];
    __shared__ int hist[512];
    __shared__ int scan_[512];
    __shared__ int cur[512];
    int b = blockIdx.x;
    int tid = threadIdx.x;
    // inclusive prefix of clamped bucket sizes over 256 entries
    if (tid < NBUCK) sb[tid] = min(bcur[tid], BCAP);
    __syncthreads();
    for (int d = 1; d < NBUCK; d <<= 1) {
        int t = 0;
        if (tid < NBUCK && tid >= d) t = sb[tid - d];
        __syncthreads();
        if (tid < NBUCK) sb[tid] += t;
        __syncthreads();
    }
    int sz = min(bcur[b], BCAP);
    int base = (b == 0) ? 0 : sb[b - 1];
    int n0 = b * NPB;
    int nn = min(NPB, N - n0);
    const unsigned* se = staging + (size_t)b * BCAP;

    hist[tid] = 0;
    __syncthreads();
    for (int i = tid; i < sz; i += 512)
        atomicAdd(&hist[se[i] >> 20], 1);
    __syncthreads();
    int h = hist[tid];
    scan_[tid] = h;
    __syncthreads();
    for (int d = 1; d < 512; d <<= 1) {
        int t = 0;
        if (tid >= d) t = scan_[tid - d];
        __syncthreads();
        scan_[tid] += t;
        __syncthreads();
    }
    int excl = scan_[tid] - h;
    cur[tid] = excl;
    if (tid < nn) {
        int node = n0 + tid;
        offs[node] = base + excl;
        counts[node] = h;
        dinv[node] = rsqrtf((float)(h + 1));  // +1 self-loop
    }
    __syncthreads();
    for (int i = tid; i < sz; i += 512) {
        unsigned p = se[i];
        int pos = atomicAdd(&cur[p >> 20], 1);
        csr_src[base + pos] = (int)(p & 0xFFFFFu);
    }
}

// xwd(bf16) = (x @ W1) * dinv[node].  4 threads/node x 8 cols; grid (N+63)/64.
__global__ __launch_bounds__(256) void gemm1_kernel(
        const float* __restrict__ x, const float* __restrict__ W1,
        const float* __restrict__ dinv, unsigned* __restrict__ xwd, int N) {
    __shared__ float ws_[128 * 32];
    for (int i = threadIdx.x; i < 128 * 32; i += blockDim.x) ws_[i] = W1[i];
    __syncthreads();
    int t = threadIdx.x;
    int node = blockIdx.x * 64 + (t >> 2);
    if (node >= N) return;
    int jq = (t & 3) * 8;  // 8 output cols
    float acc[8];
#pragma unroll
    for (int j = 0; j < 8; ++j) acc[j] = 0.0f;
    const float4* xr = (const float4*)(x + (size_t)node * 128);
#pragma unroll 4
    for (int k4 = 0; k4 < 32; ++k4) {
        float4 xv = xr[k4];
        const float* wb = ws_ + (k4 * 4) * 32 + jq;
        float4 a0 = *(const float4*)(wb);
        float4 a1 = *(const float4*)(wb + 4);
        float4 b0 = *(const float4*)(wb + 32);
        float4 b1v = *(const float4*)(wb + 36);
        float4 c0 = *(const float4*)(wb + 64);
        float4 c1 = *(const float4*)(wb + 68);
        float4 d0 = *(const float4*)(wb + 96);
        float4 d1 = *(const float4*)(wb + 100);
        acc[0] += xv.x * a0.x + xv.y * b0.x + xv.z * c0.x + xv.w * d0.x;
        acc[1] += xv.x * a0.y + xv.y * b0.y + xv.z * c0.y + xv.w * d0.y;
        acc[2] += xv.x * a0.z + xv.y * b0.z + xv.z * c0.z + xv.w * d0.z;
        acc[3] += xv.x * a0.w + xv.y * b0.w + xv.z * c0.w + xv.w * d0.w;
        acc[4] += xv.x * a1.x + xv.y * b1v.x + xv.z * c1.x + xv.w * d1.x;
        acc[5] += xv.x * a1.y + xv.y * b1v.y + xv.z * c1.y + xv.w * d1.y;
        acc[6] += xv.x * a1.z + xv.y * b1v.z + xv.z * c1.z + xv.w * d1.z;
        acc[7] += xv.x * a1.w + xv.y * b1v.w + xv.z * c1.w + xv.w * d1.w;
    }
    float d = dinv[node];
    unsigned pk0 = f2bf(acc[0] * d) | (f2bf(acc[1] * d) << 16);
    unsigned pk1 = f2bf(acc[2] * d) | (f2bf(acc[3] * d) << 16);
    unsigned pk2 = f2bf(acc[4] * d) | (f2bf(acc[5] * d) << 16);
    unsigned pk3 = f2bf(acc[6] * d) | (f2bf(acc[7] * d) << 16);
    ((uint4*)(xwd + (size_t)node * 16))[t & 3] = make_uint4(pk0, pk1, pk2, pk3);
}

// Layer-1 aggregate, lane-slice geometry: 4 lanes own node's 64B bf16 row in
// 16B slices; serial over edges (x2 unroll); fp32 accum; no shuffles.
__global__ __launch_bounds__(256) void aggS32_kernel(
        const int* __restrict__ offs, const int* __restrict__ counts,
        const int* __restrict__ csr_src, const float* __restrict__ dinv,
        const unsigned* __restrict__ xwd, float* __restrict__ agg, int N) {
    int t = threadIdx.x;
    int q = t & 3;                       // 16B slice
    int node = blockIdx.x * 64 + (t >> 2);
    if (node >= N) return;
    int off = offs[node];
    int deg = counts[node];
    float acc[8];
    {
        uint4 v = ((const uint4*)(xwd + (size_t)node * 16))[q];  // self term
        acc[0] = bflo(v.x); acc[1] = bfhi(v.x);
        acc[2] = bflo(v.y); acc[3] = bfhi(v.y);
        acc[4] = bflo(v.z); acc[5] = bfhi(v.z);
        acc[6] = bflo(v.w); acc[7] = bfhi(v.w);
    }
    int i = 0;
    for (; i + 1 < deg; i += 2) {
        int s0 = csr_src[off + i];
        int s1 = csr_src[off + i + 1];
        uint4 v0 = ((const uint4*)(xwd + (size_t)s0 * 16))[q];
        uint4 v1 = ((const uint4*)(xwd + (size_t)s1 * 16))[q];
        acc[0] += bflo(v0.x) + bflo(v1.x); acc[1] += bfhi(v0.x) + bfhi(v1.x);
        acc[2] += bflo(v0.y) + bflo(v1.y); acc[3] += bfhi(v0.y) + bfhi(v1.y);
        acc[4] += bflo(v0.z) + bflo(v1.z); acc[5] += bfhi(v0.z) + bfhi(v1.z);
        acc[6] += bflo(v0.w) + bflo(v1.w); acc[7] += bfhi(v0.w) + bfhi(v1.w);
    }
    if (i < deg) {
        int s = csr_src[off + i];
        uint4 v = ((const uint4*)(xwd + (size_t)s * 16))[q];
        acc[0] += bflo(v.x); acc[1] += bfhi(v.x);
        acc[2] += bflo(v.y); acc[3] += bfhi(v.y);
        acc[4] += bflo(v.z); acc[5] += bfhi(v.z);
        acc[6] += bflo(v.w); acc[7] += bfhi(v.w);
    }
    float dv = dinv[node];
    float* op = agg + (size_t)node * 32 + q * 8;
    ((float4*)op)[0] = make_float4(acc[0] * dv, acc[1] * dv, acc[2] * dv, acc[3] * dv);
    ((float4*)op)[1] = make_float4(acc[4] * dv, acc[5] * dv, acc[6] * dv, acc[7] * dv);
}

// h2wd(bf16) = (relu(agg1 + b1) @ W2) * dinv[node]
__global__ void gemm2_kernel(const float* __restrict__ agg1, const float* __restrict__ W2,
                             const float* __restrict__ b1, const float* __restrict__ dinv,
                             unsigned* __restrict__ h2wd, int N) {
    __shared__ float ws_[32 * 16];
    __shared__ float bs_[32];
    for (int i = threadIdx.x; i < 32 * 16; i += blockDim.x) ws_[i] = W2[i];
    if (threadIdx.x < 32) bs_[threadIdx.x] = b1[threadIdx.x];
    __syncthreads();
    int node = blockIdx.x * blockDim.x + threadIdx.x;
    if (node >= N) return;
    float h[32];
    const float4* ar = (const float4*)(agg1 + (size_t)node * 32);
#pragma unroll
    for (int k4 = 0; k4 < 8; ++k4) {
        float4 v = ar[k4];
        h[k4 * 4 + 0] = fmaxf(v.x + bs_[k4 * 4 + 0], 0.0f);
        h[k4 * 4 + 1] = fmaxf(v.y + bs_[k4 * 4 + 1], 0.0f);
        h[k4 * 4 + 2] = fmaxf(v.z + bs_[k4 * 4 + 2], 0.0f);
        h[k4 * 4 + 3] = fmaxf(v.w + bs_[k4 * 4 + 3], 0.0f);
    }
    float acc[16];
#pragma unroll
    for (int j = 0; j < 16; ++j) acc[j] = 0.0f;
#pragma unroll
    for (int k = 0; k < 32; ++k) {
        float hv = h[k];
#pragma unroll
        for (int j4 = 0; j4 < 4; ++j4) {
            float4 w = *(const float4*)(ws_ + k * 16 + j4 * 4);
            acc[j4 * 4 + 0] += hv * w.x;
            acc[j4 * 4 + 1] += hv * w.y;
            acc[j4 * 4 + 2] += hv * w.z;
            acc[j4 * 4 + 3] += hv * w.w;
        }
    }
    float d = dinv[node];
    unsigned pk[8];
#pragma unroll
    for (int j = 0; j < 8; ++j)
        pk[j] = f2bf(acc[2 * j] * d) | (f2bf(acc[2 * j + 1] * d) << 16);
    uint4* hp = (uint4*)(h2wd + (size_t)node * 8);
    hp[0] = make_uint4(pk[0], pk[1], pk[2], pk[3]);
    hp[1] = make_uint4(pk[4], pk[5], pk[6], pk[7]);
}

// Layer-2 aggregate + fused head, lane-slice: 2 lanes own node's 32B row;
// serial edges (x2 unroll); epilogue = 8 FMA dot + ONE shfl_xor -> out.
__global__ __launch_bounds__(256) void aggS16f_kernel(
        const int* __restrict__ offs, const int* __restrict__ counts,
        const int* __restrict__ csr_src, const float* __restrict__ dinv,
        const unsigned* __restrict__ h2wd,
        const float* __restrict__ b2, const float* __restrict__ Wf,
        const float* __restrict__ bf, float* __restrict__ out, int N) {
    __shared__ float bs_[16];
    __shared__ float wf_[16];
    __shared__ float bfv;
    int t = threadIdx.x;
    if (t < 16) { bs_[t] = b2[t]; wf_[t] = Wf[t]; }
    if (t == 0) bfv = bf[0];
    __syncthreads();
    int q = t & 1;                        // 16B slice (8 feats)
    int node = blockIdx.x * 128 + (t >> 1);
    if (node >= N) return;
    int off = offs[node];
    int deg = counts[node];
    float acc[8];
    {
        uint4 v = ((const uint4*)(h2wd + (size_t)node * 8))[q];  // self term
        acc[0] = bflo(v.x); acc[1] = bfhi(v.x);
        acc[2] = bflo(v.y); acc[3] = bfhi(v.y);
        acc[4] = bflo(v.z); acc[5] = bfhi(v.z);
        acc[6] = bflo(v.w); acc[7] = bfhi(v.w);
    }
    int i = 0;
    for (; i + 1 < deg; i += 2) {
        int s0 = csr_src[off + i];
        int s1 = csr_src[off + i + 1];
        uint4 v0 = ((const uint4*)(h2wd + (size_t)s0 * 8))[q];
        uint4 v1 = ((const uint4*)(h2wd + (size_t)s1 * 8))[q];
        acc[0] += bflo(v0.x) + bflo(v1.x); acc[1] += bfhi(v0.x) + bfhi(v1.x);
        acc[2] += bflo(v0.y) + bflo(v1.y); acc[3] += bfhi(v0.y) + bfhi(v1.y);
        acc[4] += bflo(v0.z) + bflo(v1.z); acc[5] += bfhi(v0.z) + bfhi(v1.z);
        acc[6] += bflo(v0.w) + bflo(v1.w); acc[7] += bfhi(v0.w) + bfhi(v1.w);
    }
    if (i < deg) {
        int s = csr_src[off + i];
        uint4 v = ((const uint4*)(h2wd + (size_t)s * 8))[q];
        acc[0] += bflo(v.x); acc[1] += bfhi(v.x);
        acc[2] += bflo(v.y); acc[3] += bfhi(v.y);
        acc[4] += bflo(v.z); acc[5] += bfhi(v.z);
        acc[6] += bflo(v.w); acc[7] += bfhi(v.w);
    }
    // fused head: out[node] = relu(acc*dv + b2) . Wf + bf  (pair-split dot)
    float dv = dinv[node];
    const float* bq = bs_ + q * 8;
    const float* wq = wf_ + q * 8;
    float part = 0.f;
#pragma unroll
    for (int k = 0; k < 8; ++k)
        part += fmaxf(acc[k] * dv + bq[k], 0.f) * wq[k];
    part += __shfl_xor(part, 1, 64);  // combine the pair's halves
    if (q == 0) out[node] = part + bfv;
}

extern "C" void kernel_launch(void* const* d_in, const int* in_sizes, int n_in,
                              void* d_out, int out_size, void* d_ws, size_t ws_size,
                              hipStream_t stream) {
    const float* x  = (const float*)d_in[0];
    const int*   ei = (const int*)d_in[1];
    const float* W1 = (const float*)d_in[2];
    const float* b1 = (const float*)d_in[3];
    const float* W2 = (const float*)d_in[4];
    const float* b2 = (const float*)d_in[5];
    const float* Wf = (const float*)d_in[6];
    const float* bf = (const float*)d_in[7];

    int N = in_sizes[0] / 128;
    int E = in_sizes[1] / 2;
    const int* src = ei;       // edge_index[0]
    const int* dst = ei + E;   // edge_index[1]
    int NPB = (N + NBUCK - 1) / NBUCK;  // 391 for N=100k

    // Workspace layout
    size_t Np = ((size_t)N + 3) & ~(size_t)3;
    size_t Ep = ((size_t)E + 3) & ~(size_t)3;
    int* wsI      = (int*)d_ws;
    int* counts   = wsI;                 // N
    int* offs     = counts + Np;         // N
    int* bcur     = offs + Np;           // 256
    int* csr_src  = bcur + NBUCK;        // E
    float* dinv   = (float*)(csr_src + Ep);      // N
    unsigned* xwd = (unsigned*)(dinv + Np);      // 16*N u32 (bf16 rows, 64B)
    float* agg1   = (float*)(xwd + 16 * Np);     // 32*N f32
    unsigned* h2wd= (unsigned*)(agg1 + 32 * Np); // 8*N u32 (bf16 rows, 32B)
    float* out    = (float*)d_out;
    // Staging (16.8 MB) aliases agg1+h2wd (16 MB) + tail: written by binA2,
    // read last by buildB; agg1 first written by aggS32 (later). No overlap.
    unsigned* staging = (unsigned*)agg1;

    int nbG1 = (N + 63) / 64;    // 4 threads/node
    int nbC  = (E + CHUNK - 1) / CHUNK;
    int nbN  = (N + TPB - 1) / TPB;
    int nbA32 = (N + 63) / 64;   // 64 nodes/block (4 lanes/node)
    int nbA16 = (N + 127) / 128; // 128 nodes/block (2 lanes/node)

    hipMemsetAsync(bcur, 0, NBUCK * sizeof(int), stream);
    binA2_kernel<<<nbC, 512, 0, stream>>>(src, dst, bcur, staging, E, NPB);
    buildB_kernel<<<NBUCK, 512, 0, stream>>>(bcur, staging, offs, counts,
                                             dinv, csr_src, N, NPB);
    gemm1_kernel<<<nbG1, 256, 0, stream>>>(x, W1, dinv, xwd, N);
    aggS32_kernel<<<nbA32, 256, 0, stream>>>(offs, counts, csr_src, dinv, xwd, agg1, N);
    gemm2_kernel<<<nbN, TPB, 0, stream>>>(agg1, W2, b1, dinv, h2wd, N);
    aggS16f_kernel<<<nbA16, 256, 0, stream>>>(offs, counts, csr_src, dinv, h2wd,
                                              b2, Wf, bf, out, N);
}